// Round 14
// baseline (2812.543 us; speedup 1.0000x reference)
//
#include <hip/hip_runtime.h>
#include <stdint.h>
#include <math.h>

// RNN predictor: B=2048, T=1024 teacher + FUT=64 AR, H=128.
// Round-14: fully register-resident recurrence, ONE WAVE = 16 samples.
//  - Transposed MFMA (R13): S^T = W.h^T. C lane (g,l15) holds S[j][sample=l15]
//    for j = 16t+4g+r; B lane (g,l15) slot (kt,e) holds h[k] -- SAME lane,
//    same sample. Slot bijection s(j): kt=q&3, e=2r+(q>>2) (j=16q+4g+r) makes
//    h' -> next B a pure in-lane register pack (16 cvt_f16 pairs + or).
//    Inverse applied to the W gather: k(kt,e) = 16*(kt+4*(e&1))+4g+(e>>1).
//  - NO LDS h-buffer, NO barriers, no cross-lane except 2 shfl_xor for o.
//  - W = Whi + 2^-12*Wlo fp16 (R11-verified numerics), 256 AGPRs consumed
//    in place by inline-asm MFMA ("a" operands; s_nop 2 heads, tied s_nop
//    fence before acc reads -- R8/R9-proven hazard discipline).
//  - o = W_out.h: 32 in-lane fma + xor16/32 -> every lane holds its sample's
//    o -> AR feedback is a register move. Output via small LDS ring (wave-
//    local, program-ordered, no barrier), flushed 64 steps at a time.
//  - grid 128 x 64 threads: 128 independent waves, one per CU. Latency-bound
//    recurrence: idle CUs are free; wall = one wave's issue stream.

#define TLEN  1024
#define FUT   64
#define HID   128
#define NSTEP (TLEN + FUT)

typedef float f32x4 __attribute__((ext_vector_type(4)));
typedef _Float16 f16x8 __attribute__((ext_vector_type(8)));
typedef uint32_t u32x4 __attribute__((ext_vector_type(4)));

__device__ __forceinline__ float fast_tanh(float v) {
    return 1.0f - 2.0f / (__expf(2.0f * v) + 1.0f);   // saturates correctly
}
__device__ __forceinline__ uint32_t pack16(float a, float b) {
    const _Float16 qa = (_Float16)a, qb = (_Float16)b;   // RNE cvt
    return (uint32_t)__builtin_bit_cast(unsigned short, qa)
         | ((uint32_t)__builtin_bit_cast(unsigned short, qb) << 16);
}

// One j-tile: 8 MFMA (4 hi + 4 lo chains), W read from AGPR in place.
// s_nop 2 head covers VALU(B-pack/acc-init) -> MFMA src hazard.
#define TILE(aH, aL, WHt, WLt, BC)                                      \
    asm volatile(                                                       \
        "s_nop 2\n\t"                                                   \
        "v_mfma_f32_16x16x32_f16 %0, %2, %10, %0\n\t"                   \
        "v_mfma_f32_16x16x32_f16 %0, %3, %11, %0\n\t"                   \
        "v_mfma_f32_16x16x32_f16 %0, %4, %12, %0\n\t"                   \
        "v_mfma_f32_16x16x32_f16 %0, %5, %13, %0\n\t"                   \
        "v_mfma_f32_16x16x32_f16 %1, %6, %10, %1\n\t"                   \
        "v_mfma_f32_16x16x32_f16 %1, %7, %11, %1\n\t"                   \
        "v_mfma_f32_16x16x32_f16 %1, %8, %12, %1\n\t"                   \
        "v_mfma_f32_16x16x32_f16 %1, %9, %13, %1"                       \
        : "+v"(aH), "+v"(aL)                                            \
        : "a"((WHt)[0]), "a"((WHt)[1]), "a"((WHt)[2]), "a"((WHt)[3]),   \
          "a"((WLt)[0]), "a"((WLt)[1]), "a"((WLt)[2]), "a"((WLt)[3]),   \
          "v"((BC)[0]), "v"((BC)[1]), "v"((BC)[2]), "v"((BC)[3]))

#define EPI(T, aH, aL)                                                      \
    do {                                                                    \
        hv[T][0] = fast_tanh(fmaf(CLO, aL[0], aH[0]) + fmaf(in, wih[T][0], bias[T][0])); \
        hv[T][1] = fast_tanh(fmaf(CLO, aL[1], aH[1]) + fmaf(in, wih[T][1], bias[T][1])); \
        hv[T][2] = fast_tanh(fmaf(CLO, aL[2], aH[2]) + fmaf(in, wih[T][2], bias[T][2])); \
        hv[T][3] = fast_tanh(fmaf(CLO, aL[3], aH[3]) + fmaf(in, wih[T][3], bias[T][3])); \
        op = fmaf(hv[T][0], wout[T][0], op);                                \
        op = fmaf(hv[T][1], wout[T][1], op);                                \
        op = fmaf(hv[T][2], wout[T][2], op);                                \
        op = fmaf(hv[T][3], wout[T][3], op);                                \
    } while (0)

__global__ __launch_bounds__(64, 1) void rnn_kernel(
    const float* __restrict__ x,      // [B, T]
    const float* __restrict__ W_ih,   // [H, 1]
    const float* __restrict__ W_hh,   // [H, H]
    const float* __restrict__ b_ih,   // [H]
    const float* __restrict__ b_hh,   // [H]
    const float* __restrict__ W_out,  // [1, H]
    const float* __restrict__ b_out,  // [1]
    float* __restrict__ out)          // [B, T+FUT]
{
    __shared__ float ring[16][68];    // o ring; row 272B: writes 2-way banks

    const int lane = threadIdx.x & 63;
    const int g    = lane >> 4;
    const int l15  = lane & 15;       // sample column
    const int s0   = blockIdx.x * 16;
    const size_t sample = s0 + l15;

    // ---- W fragments (fp16 hi/lo), homed in 256 AGPRs ----
    f16x8 WH[8][4], WL[8][4];
    #pragma unroll
    for (int t = 0; t < 8; ++t) {
        const float* row = W_hh + (size_t)(16 * t + l15) * HID;  // A row m=l15
        #pragma unroll
        for (int kt = 0; kt < 4; ++kt) {
            #pragma unroll
            for (int e = 0; e < 8; ++e) {
                const int k = 16 * (kt + 4 * (e & 1)) + 4 * g + (e >> 1);
                const float w = row[k];
                const _Float16 wh = (_Float16)w;
                WH[t][kt][e] = wh;
                WL[t][kt][e] = (_Float16)((w - (float)wh) * 4096.0f);
            }
        }
    }
    // per-lane C-row constants: j = 16t + 4g + r
    float bias[8][4], wih[8][4], wout[8][4];
    #pragma unroll
    for (int t = 0; t < 8; ++t)
        #pragma unroll
        for (int r = 0; r < 4; ++r) {
            const int j = 16 * t + 4 * g + r;
            bias[t][r] = b_ih[j] + b_hh[j];
            wih[t][r]  = W_ih[j];
            wout[t][r] = W_out[j];
        }
    const float bo  = b_out[0];
    const float CLO = 1.0f / 4096.0f;

    u32x4 BA[4] = {(u32x4){0,0,0,0}, (u32x4){0,0,0,0}, (u32x4){0,0,0,0}, (u32x4){0,0,0,0}};
    u32x4 BB[4] = {(u32x4){0,0,0,0}, (u32x4){0,0,0,0}, (u32x4){0,0,0,0}, (u32x4){0,0,0,0}};

    float o = 0.0f;
    float xcur = x[sample * TLEN];
    float hv[8][4];

#define STEP(I, BC, BN)                                                     \
    do {                                                                    \
        const int i = (I);                                                  \
        float xnext = 0.0f;                                                 \
        if (i + 1 < TLEN) xnext = x[sample * TLEN + i + 1];                 \
        if (i > 0 && (i & 63) == 0) {          /* flush o_{i-64..i-1} */    \
            const int base = i - 64;                                        \
            _Pragma("unroll")                                               \
            for (int ph = 0; ph < 4; ++ph) {                                \
                const int s = lane >> 2;                                    \
                const int c = (lane & 3) * 4 + ph * 16;                     \
                const f32x4 v = *(const f32x4*)&ring[s][c];                 \
                *(f32x4*)&out[(size_t)(s0 + s) * NSTEP + base + c] = v;     \
            }                                                               \
        }                                                                   \
        const float in = (i < TLEN) ? xcur : o;                             \
        f32x4 z = {0.f, 0.f, 0.f, 0.f};                                     \
        f32x4 aH0=z,aH1=z,aH2=z,aH3=z,aH4=z,aH5=z,aH6=z,aH7=z;              \
        f32x4 aL0=z,aL1=z,aL2=z,aL3=z,aL4=z,aL5=z,aL6=z,aL7=z;              \
        TILE(aH0, aL0, WH[0], WL[0], BC);                                   \
        TILE(aH1, aL1, WH[1], WL[1], BC);                                   \
        TILE(aH2, aL2, WH[2], WL[2], BC);                                   \
        TILE(aH3, aL3, WH[3], WL[3], BC);                                   \
        TILE(aH4, aL4, WH[4], WL[4], BC);                                   \
        TILE(aH5, aL5, WH[5], WL[5], BC);                                   \
        TILE(aH6, aL6, WH[6], WL[6], BC);                                   \
        TILE(aH7, aL7, WH[7], WL[7], BC);                                   \
        /* fence: pin every acc read past MFMA D->VALU wait-state window */ \
        asm volatile("s_nop 7\n\ts_nop 7"                                   \
            : "+v"(aH0), "+v"(aH1), "+v"(aH2), "+v"(aH3),                   \
              "+v"(aH4), "+v"(aH5), "+v"(aH6), "+v"(aH7),                   \
              "+v"(aL0), "+v"(aL1), "+v"(aL2), "+v"(aL3),                   \
              "+v"(aL4), "+v"(aL5), "+v"(aL6), "+v"(aL7));                  \
        float op = 0.0f;                                                    \
        EPI(0, aH0, aL0); EPI(1, aH1, aL1); EPI(2, aH2, aL2);               \
        EPI(3, aH3, aL3); EPI(4, aH4, aL4); EPI(5, aH5, aL5);               \
        EPI(6, aH6, aL6); EPI(7, aH7, aL7);                                 \
        _Pragma("unroll")                                                   \
        for (int kt = 0; kt < 4; ++kt) {      /* h' -> next-step B frags */ \
            u32x4 bn;                                                       \
            bn[0] = pack16(hv[kt][0], hv[kt + 4][0]);                       \
            bn[1] = pack16(hv[kt][1], hv[kt + 4][1]);                       \
            bn[2] = pack16(hv[kt][2], hv[kt + 4][2]);                       \
            bn[3] = pack16(hv[kt][3], hv[kt + 4][3]);                       \
            (BN)[kt] = bn;                                                  \
        }                                                                   \
        op += __shfl_xor(op, 16);                                           \
        op += __shfl_xor(op, 32);                                           \
        o = op + bo;                          /* all lanes: o(sample l15) */\
        if (lane < 16) ring[l15][i & 63] = o;                               \
        xcur = xnext;                                                       \
    } while (0)

    for (int ii = 0; ii < NSTEP; ii += 2) {
        STEP(ii,     BA, BB);
        STEP(ii + 1, BB, BA);
    }

    // tail: flush o_{1024..1087}
    {
        const int base = TLEN;
        #pragma unroll
        for (int ph = 0; ph < 4; ++ph) {
            const int s = lane >> 2;
            const int c = (lane & 3) * 4 + ph * 16;
            const f32x4 v = *(const f32x4*)&ring[s][c];
            *(f32x4*)&out[(size_t)(s0 + s) * NSTEP + base + c] = v;
        }
    }
#undef STEP
}

extern "C" void kernel_launch(void* const* d_in, const int* in_sizes, int n_in,
                              void* d_out, int out_size, void* d_ws, size_t ws_size,
                              hipStream_t stream) {
    const float* x     = (const float*)d_in[0];
    const float* W_ih  = (const float*)d_in[1];
    const float* W_hh  = (const float*)d_in[2];
    const float* b_ih  = (const float*)d_in[3];
    const float* b_hh  = (const float*)d_in[4];
    const float* W_out = (const float*)d_in[5];
    const float* b_out = (const float*)d_in[6];
    float* out = (float*)d_out;

    dim3 grid(2048 / 16);   // 128 waves, one per block
    dim3 block(64);
    rnn_kernel<<<grid, block, 0, stream>>>(x, W_ih, W_hh, b_ih, b_hh,
                                           W_out, b_out, out);
}

// Round 15
// 759.572 us; speedup vs baseline: 3.7028x; 3.7028x over previous
//
#include <hip/hip_runtime.h>
#include <stdint.h>
#include <math.h>

// RNN predictor: B=2048, T=1024 teacher + FUT=64 AR, H=128.
// Round-15: M=16 fully sample-filled, 8 waves x one 16-col j-tile each.
//  - Per wave-step: 8 S-MFMA (fp16 hi/lo W, single-fp16 h -- R11-verified)
//    + 8 o-MFMA (wout as hi/lo B-frag, col 0 only) on the SAME A-frags.
//    o_{i-1} = wout.h_i emerges mid-step: ring-write in teacher phase,
//    4 shfl broadcast in AR phase. NO shfl-reduce, NO opart, NO o-VALU.
//  - Per CU-step: 16 samples for 128 MFMA + one shared 4KB h read
//    (8 waves x 4 ds_read_b128, granule-XOR swizzle = optimal 8cyc each).
//  - Epilogue/lane: 4x (2 fma + tanh + cvt + ds_write_b16). h' writes <=2-way.
//  - grid 128 x 512 thr: 1 block/CU on 128 CUs, 2 waves/SIMD,
//    __launch_bounds__(512,2). One barrier/step.

#define TLEN  1024
#define FUT   64
#define HID   128
#define SPB   16
#define NT    512
#define NSTEP (TLEN + FUT)

typedef float f32x4 __attribute__((ext_vector_type(4)));
typedef _Float16 f16x8 __attribute__((ext_vector_type(8)));
typedef uint32_t u32x4 __attribute__((ext_vector_type(4)));

__device__ __forceinline__ f16x8 asf16(u32x4 v) {
    return __builtin_bit_cast(f16x8, v);
}
__device__ __forceinline__ float fast_tanh(float v) {
    return 1.0f - 2.0f / (__expf(2.0f * v) + 1.0f);   // saturates correctly
}

__global__ __launch_bounds__(NT, 2) void rnn_kernel(
    const float* __restrict__ x,      // [B, T]
    const float* __restrict__ W_ih,   // [H, 1]
    const float* __restrict__ W_hh,   // [H, H]
    const float* __restrict__ b_ih,   // [H]
    const float* __restrict__ b_hh,   // [H]
    const float* __restrict__ W_out,  // [1, H]
    const float* __restrict__ b_out,  // [1]
    float* __restrict__ out)          // [B, T+FUT]
{
    // h: [p][row s=0..15][k] fp16; byte(s,k) = s*256 + ((2k) ^ ((s&7)<<4))
    __shared__ __align__(16) unsigned short hbuf[2][SPB * HID];
    __shared__ __align__(16) float xstg[128][SPB];      // [t][sample]
    __shared__ __align__(16) float ring[2][SPB][68];    // o ring, padded

    const int tid  = threadIdx.x;
    const int lane = tid & 63;
    const int wid  = tid >> 6;        // wave w: j-tile cols 16w..16w+15
    const int l15  = lane & 15;
    const int g    = lane >> 4;
    const int s0   = blockIdx.x * SPB;

    // ---- weight B-fragments: col j = 16*wid + l15, k = 32kt + 8g + e ----
    const int j = 16 * wid + l15;
    f16x8 Wh[4], Wl[4], Oh[4], Ol[4];
    {
        const float* wr = W_hh + (size_t)j * HID;
        #pragma unroll
        for (int kt = 0; kt < 4; ++kt) {
            #pragma unroll
            for (int e = 0; e < 8; ++e) {
                const int k = 32 * kt + 8 * g + e;
                const float w = wr[k];
                const _Float16 wh = (_Float16)w;
                Wh[kt][e] = wh;
                Wl[kt][e] = (_Float16)((w - (float)wh) * 4096.0f);
                const float wo = (l15 == 0) ? W_out[k] : 0.0f;   // B col 0 only
                const _Float16 oh = (_Float16)wo;
                Oh[kt][e] = oh;
                Ol[kt][e] = (_Float16)((wo - (float)oh) * 4096.0f);
            }
        }
    }
    const float bias = b_ih[j] + b_hh[j];
    const float wih  = W_ih[j];
    const float bo   = b_out[0];
    const float CLO  = 1.0f / 4096.0f;

    // ---- LDS byte offsets ----
    int aoff[4];   // A-read: row l15, 16B at granule (4kt+g) ^ (l15&7)
    #pragma unroll
    for (int kt = 0; kt < 4; ++kt)
        aoff[kt] = l15 * 256 + (((4 * kt + g) << 4) ^ ((l15 & 7) << 4));
    int woff[4];   // h'-write: row 4g+r, byte 2j, swizzled
    #pragma unroll
    for (int r = 0; r < 4; ++r) {
        const int row = 4 * g + r;
        woff[r] = row * 256 + ((2 * j) ^ ((row & 7) << 4));
    }

    for (int idx = tid; idx < SPB * HID; idx += NT)   // both parities (u32)
        ((uint32_t*)hbuf)[idx] = 0;
    __syncthreads();

    for (int i = 0; i < NSTEP; ++i) {
        const int p = i & 1;

        // refill x chunk every 128 teacher steps (coalesced along t)
        if (i < TLEN && (i & 127) == 0) {
            #pragma unroll
            for (int pass = 0; pass < 4; ++pass) {
                const int idx = pass * NT + tid;
                const int t = idx & 127, s = idx >> 7;
                xstg[t][s] = x[(size_t)(s0 + s) * TLEN + (i + t)];
            }
            __syncthreads();
        }

        // flush a full 64-entry output ring (o_{i-65}..o_{i-2})
        if (i > 64 && (i & 63) == 1 && tid < 16 * SPB) {
            const int q = ((i - 65) >> 6) & 1;
            const int s = tid >> 4, c4 = (tid & 15) * 4;
            const f32x4 v = *(const f32x4*)&ring[q][s][c4];
            *(f32x4*)&out[(size_t)(s0 + s) * NSTEP + (i - 65) + c4] = v;
        }

        // A-fragments of h_i: all 16 rows real, all lanes read
        const char* hb = (const char*)hbuf[p];
        u32x4 A_[4];
        #pragma unroll
        for (int kt = 0; kt < 4; ++kt)
            A_[kt] = *(const u32x4*)(hb + aoff[kt]);

        // 16 MFMA in 4 independent chains: S (hi,lo) + o (hi,lo)
        f32x4 sH = {0.f,0.f,0.f,0.f}, sL = sH, oH = sH, oL = sH;
        #pragma unroll
        for (int kt = 0; kt < 4; ++kt) {
            sH = __builtin_amdgcn_mfma_f32_16x16x32_f16(asf16(A_[kt]), Wh[kt], sH, 0, 0, 0);
            sL = __builtin_amdgcn_mfma_f32_16x16x32_f16(asf16(A_[kt]), Wl[kt], sL, 0, 0, 0);
            oH = __builtin_amdgcn_mfma_f32_16x16x32_f16(asf16(A_[kt]), Oh[kt], oH, 0, 0, 0);
            oL = __builtin_amdgcn_mfma_f32_16x16x32_f16(asf16(A_[kt]), Ol[kt], oL, 0, 0, 0);
        }

        // o_{i-1}[4g+r] = oval[r] + bo, valid at lanes l15==0
        float oval[4];
        #pragma unroll
        for (int r = 0; r < 4; ++r) oval[r] = fmaf(CLO, oL[r], oH[r]) + bo;

        if (i > 0 && wid == 0 && l15 == 0) {
            const int q = ((i - 1) >> 6) & 1;
            const int c = (i - 1) & 63;
            #pragma unroll
            for (int r = 0; r < 4; ++r) ring[q][4 * g + r][c] = oval[r];
        }

        // per-lane inputs for samples 4g+r (uniform branch)
        f32x4 inv;
        if (i < TLEN) {
            inv = *(const f32x4*)&xstg[i & 127][4 * g];
        } else {
            #pragma unroll
            for (int r = 0; r < 4; ++r) inv[r] = __shfl(oval[r], g << 4);
        }

        // epilogue: 4 samples x this lane's single col j
        char* hw = (char*)hbuf[p ^ 1];
        #pragma unroll
        for (int r = 0; r < 4; ++r) {
            const float S = fmaf(CLO, sL[r], sH[r]) + fmaf(inv[r], wih, bias);
            const float h = fast_tanh(S);
            const _Float16 q16 = (_Float16)h;   // RNE
            *(unsigned short*)(hw + woff[r]) = __builtin_bit_cast(unsigned short, q16);
        }
        __syncthreads();   // the one per-step barrier
    }

    // tail: o_{NSTEP-1} from final state (parity NSTEP&1 = 0)
    {
        const char* hb = (const char*)hbuf[NSTEP & 1];
        u32x4 A_[4];
        #pragma unroll
        for (int kt = 0; kt < 4; ++kt)
            A_[kt] = *(const u32x4*)(hb + aoff[kt]);
        f32x4 oH = {0.f,0.f,0.f,0.f}, oL = oH;
        #pragma unroll
        for (int kt = 0; kt < 4; ++kt) {
            oH = __builtin_amdgcn_mfma_f32_16x16x32_f16(asf16(A_[kt]), Oh[kt], oH, 0, 0, 0);
            oL = __builtin_amdgcn_mfma_f32_16x16x32_f16(asf16(A_[kt]), Ol[kt], oL, 0, 0, 0);
        }
        if (wid == 0 && l15 == 0) {
            #pragma unroll
            for (int r = 0; r < 4; ++r)
                ring[0][4 * g + r][63] = fmaf(CLO, oL[r], oH[r]) + bo;
        }
    }
    __syncthreads();
    if (tid < 16 * SPB) {   // flush t = 1024..1087 (ring parity 0)
        const int s = tid >> 4, c4 = (tid & 15) * 4;
        const f32x4 v = *(const f32x4*)&ring[0][s][c4];
        *(f32x4*)&out[(size_t)(s0 + s) * NSTEP + TLEN + c4] = v;
    }
}

extern "C" void kernel_launch(void* const* d_in, const int* in_sizes, int n_in,
                              void* d_out, int out_size, void* d_ws, size_t ws_size,
                              hipStream_t stream) {
    const float* x     = (const float*)d_in[0];
    const float* W_ih  = (const float*)d_in[1];
    const float* W_hh  = (const float*)d_in[2];
    const float* b_ih  = (const float*)d_in[3];
    const float* b_hh  = (const float*)d_in[4];
    const float* W_out = (const float*)d_in[5];
    const float* b_out = (const float*)d_in[6];
    float* out = (float*)d_out;

    dim3 grid(2048 / SPB);   // 128 blocks of 512 threads
    dim3 block(NT);
    rnn_kernel<<<grid, block, 0, stream>>>(x, W_ih, W_hh, b_ih, b_hh,
                                           W_out, b_out, out);
}